// Round 11
// baseline (329.563 us; speedup 1.0000x reference)
//
#include <hip/hip_runtime.h>

#define TSTEPS 1023
#define GAMMA  (0.01f / 32.0f)   // LR * dL/dy scale: 2/(64*2) folded
#define EPSV   1e-5f

// workspace layout (float offsets)
#define WS_HS 0       // 64*64 hs table
#define WS_G  4096    // 64*64 PRE-SCALED gram: Gs = GAMMA*G + GAMMA
#define WS_Z0 8192    // 64*16 initial Ztilde = hs@w1 + b1

typedef float v2f __attribute__((ext_vector_type(2)));
typedef unsigned int v2u __attribute__((ext_vector_type(2)));

template<int CTRL>
__device__ __forceinline__ float dppmov(float x) {
    return __int_as_float(__builtin_amdgcn_update_dpp(0, __float_as_int(x), CTRL, 0xF, 0xF, true));
}
__device__ __forceinline__ v2u swap16(float a, float b) {
    return __builtin_amdgcn_permlane16_swap(__float_as_uint(a), __float_as_uint(b), false, false);
}
__device__ __forceinline__ v2u swap32(float a, float b) {
    return __builtin_amdgcn_permlane32_swap(__float_as_uint(a), __float_as_uint(b), false, false);
}
__device__ __forceinline__ float rlane(float v, int sl) {
    return __int_as_float(__builtin_amdgcn_readlane(__float_as_int(v), sl));
}
#define U2F(x) __uint_as_float(x)

// Raw barrier WITHOUT the lgkmcnt(0) drain __syncthreads emits (R10-verified:
// LDS pipe services requests in arrival order, so the pre-barrier ypart write
// is ordered ahead of post-release reads). Saves ~50cy/step write-retire drain.
__device__ __forceinline__ void xbar() {
    asm volatile("" ::: "memory");
    __builtin_amdgcn_s_barrier();
    asm volatile("" ::: "memory");
}

// ---------------- kernel A: hs table (per-token embed->FFN->LN), 64 blocks ----------------
__global__ void hs_kernel(const float* __restrict__ embed,
                          const float* __restrict__ ffw1, const float* __restrict__ ffb1,
                          const float* __restrict__ ffw2, const float* __restrict__ ffb2,
                          const float* __restrict__ lng,  const float* __restrict__ lnb,
                          float* __restrict__ ws) {
    __shared__ float e[64];
    __shared__ float a1[128];
    int w = blockIdx.x;
    int tid = threadIdx.x;
    if (tid < 64) e[tid] = embed[w * 64 + tid];
    __syncthreads();
    float z1 = ffb1[tid];
    for (int x = 0; x < 64; ++x) z1 += e[x] * ffw1[x * 128 + tid];
    a1[tid] = fmaxf(z1, 0.0f);
    __syncthreads();
    if (tid < 64) {
        float f = ffb2[tid];
        for (int i = 0; i < 128; ++i) f += a1[i] * ffw2[i * 64 + tid];
        float hv = e[tid] + f;
        float s = hv;
#pragma unroll
        for (int m = 32; m >= 1; m >>= 1) s += __shfl_xor(s, m);
        float mu = s * (1.0f / 64.0f);
        float dv = hv - mu;
        float vs = dv * dv;
#pragma unroll
        for (int m = 32; m >= 1; m >>= 1) vs += __shfl_xor(vs, m);
        float rstd = 1.0f / sqrtf(vs * (1.0f / 64.0f) + EPSV);
        ws[WS_HS + w * 64 + tid] = dv * rstd * lng[tid] + lnb[tid];
    }
}

// ---------------- kernel B: pre-scaled Gram + Ztilde0, 64 blocks ----------------
__global__ void gz_kernel(const float* __restrict__ w1, const float* __restrict__ b1,
                          float* __restrict__ ws) {
    __shared__ float row[64];
    int w = blockIdx.x, tid = threadIdx.x;
    row[tid] = ws[WS_HS + w * 64 + tid];
    __syncthreads();
    float g = 0.0f;
    for (int x = 0; x < 64; ++x) g += row[x] * ws[WS_HS + tid * 64 + x];
    ws[WS_G + w * 64 + tid] = GAMMA * g + GAMMA;      // pre-scaled
    if (tid < 16) {
        float z = b1[tid];
        for (int x = 0; x < 64; ++x) z += row[x] * w1[x * 16 + tid];
        ws[WS_Z0 + w * 16 + tid] = z;
    }
}

// ---------------- main kernel: 4-wave j-split, register Z, raw barrier (R10) + R11 trims ----------------
// R11 = R10 (verified 258us kernel) + three symmetric micro-trims:
//  (1) symmetric vv-fold: EVERY wave's ypart -= 0.25*vv (R9's failure was the
//      wave0-only asymmetric fold delaying barrier arrival); removes -vv from
//      the post-barrier d chain. d stays a fixed tree of the same 4 published
//      floats -> bitwise identical across waves.
//  (2) cr carried one step ahead: cz = rlane(cr, stkn) register-immediate at
//      barrier release; Gs[tkn] row read moves to the prefetch shadow. Peeled
//      step's carried cr = Gs[sq[2044]] row, exactly the old explicit read.
//  (3) dead tk bookkeeping removed.
struct TTT4Smem {
    float hs[4096];
    float Gs[4096];
    int   sq[2048];                 // unguarded prefetch reads sq[2048..2049] -> land in ybuf (harmless)
    float ybuf[2][4][64];           // [parity][wave][lane] y-partial exchange
    float ctxp[4][64];              // final ctx partials
};

__device__ __forceinline__ void reduce4(const v2f* a2, const v2f* p2, v2f* dz2) {
    // fold lane bit0: partner lane's slot m^2 is the same logical j
    float q0 = p2[0].x + dppmov<0xB1>(p2[1].x);
    float q1 = p2[0].y + dppmov<0xB1>(p2[1].y);
    // relu mask (slot-aligned)
    float rm0 = (a2[0].x > 0.0f) ? q0 : 0.0f;
    float rm1 = (a2[0].y > 0.0f) ? q1 : 0.0f;
    // fold b4 (encodes q-index into b4) then sum over b5
    v2u f01 = swap16(rm0, rm1);
    float T = U2F(f01[0]) + U2F(f01[1]);        // j = b4 + 2*b0, summed over b4-pair
    v2u g01 = swap32(T, T);
    T = U2F(g01[0]) + U2F(g01[1]);              // summed over b5
    // orbit sums over lane bits 1,2,3
    T = T + dppmov<0x122>(T);   // row_ror:2
    T = T + dppmov<0x124>(T);   // row_ror:4
    T = T + dppmov<0x128>(T);   // row_ror:8
    // broadcast: T = dz[b4 + 2*b0] -> all 4 slots (slot m <-> j = m ^ 2*b0)
    v2u u01 = swap16(T, T);
    const float A0 = U2F(u01[0]);               // dz[0 ^ 2b0] -> slot 0
    const float A1 = U2F(u01[1]);               // dz[1 ^ 2b0] -> slot 1
    dz2[0] = {A0, A1};
    dz2[1] = {dppmov<0xB1>(A0), dppmov<0xB1>(A1)};   // slots 2,3 (other b0)
}

__launch_bounds__(256, 1)
__global__ void ttt_kernel(const int* __restrict__ seq,
                           const float* __restrict__ w2, const float* __restrict__ b2i,
                           const float* __restrict__ outw, const float* __restrict__ outb,
                           const float* __restrict__ ws, float* __restrict__ out) {
    __shared__ TTT4Smem sm;

    const int b    = blockIdx.x;
    const int tid  = threadIdx.x;
    const int wv   = tid >> 6;
    const int lane = tid & 63;
    const int b0   = lane & 1;
    const int X    = b0 << 1;              // slot xor: logical j = 4*wv + (slot ^ X)
    const bool pb  = (b0 != 0);
    const bool wv0 = (wv == 0);

    {   // vectorized staging (256 threads)
        float4*       hv = (float4*)sm.hs;
        const float4* sv = (const float4*)(ws + WS_HS);
#pragma unroll
        for (int m = 0; m < 4; ++m) hv[m * 256 + tid] = sv[m * 256 + tid];
        float4*       gv = (float4*)sm.Gs;
        const float4* gs = (const float4*)(ws + WS_G);
#pragma unroll
        for (int m = 0; m < 4; ++m) gv[m * 256 + tid] = gs[m * 256 + tid];
        int4*       qv = (int4*)sm.sq;
        const int4* qs = (const int4*)(seq + b * 2048);
#pragma unroll
        for (int m = 0; m < 2; ++m) qv[m * 256 + tid] = qs[m * 256 + tid];
    }

    // Z state: row = lane, this wave's 4 j-columns, LOGICAL order, registers only
    v2f Zv[2];
    {
        const float4 z0 = *(const float4*)(ws + WS_Z0 + lane * 16 + 4 * wv);
        Zv[0] = {z0.x, z0.y};
        Zv[1] = {z0.z, z0.w};
    }

    // W2 in permuted slot order for this wave's j-slice
    v2f W2p[2];
#pragma unroll
    for (int i = 0; i < 2; ++i) {
        v2f w;
        w.x = w2[(4 * wv + ((2 * i) ^ X)) * 64 + lane];
        w.y = w2[(4 * wv + ((2 * i + 1) ^ X)) * 64 + lane];
        W2p[i] = w;
    }
    float ybias = wv0 ? b2i[lane] : 0.0f;     // b2 lives in wave0's y-partial only
    const float gma = wv0 ? GAMMA : 0.0f;
    __syncthreads();                          // staging barrier: full drain (kept)

    // z2 init: row sq[0] broadcast from registers via readlane, permuted slots
    const int tk0 = sm.sq[0];
    v2f z2[2];
    {
        const int stk = __builtin_amdgcn_readfirstlane(tk0);
        const float e0 = rlane(Zv[0].x, stk);
        const float e1 = rlane(Zv[0].y, stk);
        const float e2 = rlane(Zv[1].x, stk);
        const float e3 = rlane(Zv[1].y, stk);
        z2[0] = { pb ? e2 : e0, pb ? e3 : e1 };
        z2[1] = { pb ? e0 : e2, pb ? e1 : e3 };
    }
    float vv = sm.hs[sm.sq[1] * 64 + lane];
    float cr = sm.Gs[tk0 * 64 + lane];        // carried: row of current key (pre-scaled)

    int2 pairT  = *(const int2*)(sm.sq + 2);
    int2 pairT1 = *(const int2*)(sm.sq + 4);

    // main loop: steps 0..1021 (last step peeled)
#pragma unroll 2
    for (int t = 0; t < TSTEPS - 1; ++t) {
        const int tkn = pairT.x;
        const int tvn = pairT.y;
        const int par = t & 1;

        // ---- forward on own j-slice; SYMMETRIC vv quarter-fold ----
        const v2f zero2 = {0.0f, 0.0f};
        v2f a2[2];
        a2[0] = __builtin_elementwise_max(z2[0], zero2);
        a2[1] = __builtin_elementwise_max(z2[1], zero2);
        v2f accv = a2[0] * W2p[0] + a2[1] * W2p[1];
        const float ypart = ybias + accv.x + accv.y - 0.25f * vv;

        // ---- y exchange (parity ping-pong, RAW barrier: no pre-drain) ----
        sm.ybuf[par][wv][lane] = ypart;
        xbar();
        const float y0 = sm.ybuf[par][0][lane];
        const float y1 = sm.ybuf[par][1][lane];
        const float y2 = sm.ybuf[par][2][lane];
        const float y3 = sm.ybuf[par][3][lane];

        // ---- off-chain: prefetch reads + register-Z row broadcast ----
        const float vnext = sm.hs[tvn * 64 + lane];
        const float crn   = sm.Gs[tkn * 64 + lane];   // next key's Gs row (consumed next step)
        const int2 pairT2 = *(const int2*)(sm.sq + 2 * t + 6);  // t=1021 reads ybuf: unused
        const int stkn = __builtin_amdgcn_readfirstlane(tkn);
        const float e0 = rlane(Zv[0].x, stkn);      // Zv current through t-1
        const float e1 = rlane(Zv[0].y, stkn);
        const float e2 = rlane(Zv[1].x, stkn);
        const float e3 = rlane(Zv[1].y, stkn);
        const v2f E0 = { pb ? e2 : e0, pb ? e3 : e1 };   // permuted slot order
        const v2f E1 = { pb ? e0 : e2, pb ? e1 : e3 };
        const float cz = rlane(cr, stkn);           // carried cr: register-immediate

        // ---- d (fixed tree -> bitwise identical in all 4 waves; vv pre-folded) ----
        const float d = (y0 + y1) + (y2 + y3);

        // ---- p (pre-update W2) + local W2/b2 update ----
        const v2f d2 = {d, d};
        v2f p2[2];
        p2[0] = W2p[0] * d2;
        p2[1] = W2p[1] * d2;
        const float sd = GAMMA * d;
        ybias -= gma * d;
        const v2f sd2 = {sd, sd};
        W2p[0] = W2p[0] - sd2 * a2[0];
        W2p[1] = W2p[1] - sd2 * a2[1];

        // ---- cross-lane reduction + broadcast ----
        v2f dz2[2];
        reduce4(a2, p2, dz2);

        // ---- next-token state (table lag covered by cz term) ----
        const v2f cz2 = {cz, cz};
        z2[0] = E0 - cz2 * dz2[0];
        z2[1] = E1 - cz2 * dz2[1];

        // ---- prompt register-Z update (logical order) ----
        const v2f dzl0 = pb ? dz2[1] : dz2[0];
        const v2f dzl1 = pb ? dz2[0] : dz2[1];
        const v2f cr2 = {cr, cr};
        Zv[0] = Zv[0] - cr2 * dzl0;
        Zv[1] = Zv[1] - cr2 * dzl1;

        vv = vnext;
        cr = crn;
        pairT = pairT1;
        pairT1 = pairT2;
    }

    // ---- peeled final step (t = 1022): key sq[2044] (carried cr), query sq[2047] ----
    {
        const int tkn = pairT.y;                  // pairT = {sq[2046], sq[2047]}
        const v2f zero2 = {0.0f, 0.0f};
        v2f a2[2];
        a2[0] = __builtin_elementwise_max(z2[0], zero2);
        a2[1] = __builtin_elementwise_max(z2[1], zero2);
        v2f accv = a2[0] * W2p[0] + a2[1] * W2p[1];
        const float ypart = ybias + accv.x + accv.y - 0.25f * vv;   // vv = hs[sq[2045]]

        sm.ybuf[0][wv][lane] = ypart;             // 1022 even -> parity 0
        xbar();
        const float y0 = sm.ybuf[0][0][lane];
        const float y1 = sm.ybuf[0][1][lane];
        const float y2 = sm.ybuf[0][2][lane];
        const float y3 = sm.ybuf[0][3][lane];

        const int stkn = __builtin_amdgcn_readfirstlane(tkn);
        const float e0 = rlane(Zv[0].x, stkn);    // Zv current through step 1021
        const float e1 = rlane(Zv[0].y, stkn);
        const float e2 = rlane(Zv[1].x, stkn);
        const float e3 = rlane(Zv[1].y, stkn);
        const v2f E0 = { pb ? e2 : e0, pb ? e3 : e1 };
        const v2f E1 = { pb ? e0 : e2, pb ? e1 : e3 };
        const float cz = rlane(cr, stkn);         // carried cr = Gs[sq[2044]] row

        const float d = (y0 + y1) + (y2 + y3);

        const v2f d2 = {d, d};
        v2f p2[2];
        p2[0] = W2p[0] * d2;
        p2[1] = W2p[1] * d2;
        const float sd = GAMMA * d;
        ybias -= gma * d;
        const v2f sd2 = {sd, sd};
        W2p[0] = W2p[0] - sd2 * a2[0];
        W2p[1] = W2p[1] - sd2 * a2[1];

        v2f dz2[2];
        reduce4(a2, p2, dz2);

        const v2f cz2 = {cz, cz};
        z2[0] = E0 - cz2 * dz2[0];
        z2[1] = E1 - cz2 * dz2[1];
    }

    // ---- final eval: ctx partial per wave, combine, then out matvec ----
    {
        const v2f zero2 = {0.0f, 0.0f};
        v2f acc = __builtin_elementwise_max(z2[0], zero2) * W2p[0]
                + __builtin_elementwise_max(z2[1], zero2) * W2p[1];
        sm.ctxp[wv][lane] = ybias + acc.x + acc.y;
    }
    __syncthreads();                              // epilogue barrier: full drain (kept)
    if (wv0) {
        float o = outb[lane];
        for (int hh = 0; hh < 64; ++hh)
            o += (sm.ctxp[0][hh] + sm.ctxp[1][hh] + sm.ctxp[2][hh] + sm.ctxp[3][hh])
                 * outw[hh * 64 + lane];
        out[b * 64 + lane] = o;
    }
}

// ---------------- launcher ----------------
extern "C" void kernel_launch(void* const* d_in, const int* in_sizes, int n_in,
                              void* d_out, int out_size, void* d_ws, size_t ws_size,
                              hipStream_t stream) {
    const int*   seq   = (const int*)d_in[0];
    const float* embed = (const float*)d_in[1];
    const float* ffw1  = (const float*)d_in[2];
    const float* ffb1  = (const float*)d_in[3];
    const float* ffw2  = (const float*)d_in[4];
    const float* ffb2  = (const float*)d_in[5];
    const float* lng   = (const float*)d_in[6];
    const float* lnb   = (const float*)d_in[7];
    const float* w1    = (const float*)d_in[8];
    const float* b1    = (const float*)d_in[9];
    const float* w2    = (const float*)d_in[10];
    const float* b2    = (const float*)d_in[11];
    const float* outw  = (const float*)d_in[12];
    const float* outb  = (const float*)d_in[13];
    float* ws  = (float*)d_ws;
    float* out = (float*)d_out;

    hipLaunchKernelGGL(hs_kernel, dim3(64), dim3(128), 0, stream,
                       embed, ffw1, ffb1, ffw2, ffb2, lng, lnb, ws);
    hipLaunchKernelGGL(gz_kernel, dim3(64), dim3(64), 0, stream, w1, b1, ws);
    hipLaunchKernelGGL(ttt_kernel, dim3(256), dim3(256), 0, stream,
                       seq, w2, b2, outw, outb, ws, out);
}

// Round 12
// 327.653 us; speedup vs baseline: 1.0058x; 1.0058x over previous
//
#include <hip/hip_runtime.h>

#define TSTEPS 1023
#define GAMMA  (0.01f / 32.0f)   // LR * dL/dy scale: 2/(64*2) folded
#define EPSV   1e-5f

// workspace layout (float offsets)
#define WS_HS 0       // 64*64 hs table
#define WS_G  4096    // 64*64 PRE-SCALED gram: Gs = GAMMA*G + GAMMA
#define WS_Z0 8192    // 64*16 initial Ztilde = hs@w1 + b1

typedef float v2f __attribute__((ext_vector_type(2)));
typedef unsigned int v2u __attribute__((ext_vector_type(2)));

template<int CTRL>
__device__ __forceinline__ float dppmov(float x) {
    return __int_as_float(__builtin_amdgcn_update_dpp(0, __float_as_int(x), CTRL, 0xF, 0xF, true));
}
__device__ __forceinline__ v2u swap16(float a, float b) {
    return __builtin_amdgcn_permlane16_swap(__float_as_uint(a), __float_as_uint(b), false, false);
}
__device__ __forceinline__ v2u swap32(float a, float b) {
    return __builtin_amdgcn_permlane32_swap(__float_as_uint(a), __float_as_uint(b), false, false);
}
__device__ __forceinline__ float rlane(float v, int sl) {
    return __int_as_float(__builtin_amdgcn_readlane(__float_as_int(v), sl));
}
#define U2F(x) __uint_as_float(x)

// Raw barrier WITHOUT the lgkmcnt(0) drain __syncthreads emits (R10-verified:
// LDS pipe services requests in arrival order, so the pre-barrier ypart write
// is ordered ahead of post-release reads). Saves ~50cy/step write-retire drain.
__device__ __forceinline__ void xbar() {
    asm volatile("" ::: "memory");
    __builtin_amdgcn_s_barrier();
    asm volatile("" ::: "memory");
}

// ---------------- kernel A: hs table (per-token embed->FFN->LN), 64 blocks ----------------
__global__ void hs_kernel(const float* __restrict__ embed,
                          const float* __restrict__ ffw1, const float* __restrict__ ffb1,
                          const float* __restrict__ ffw2, const float* __restrict__ ffb2,
                          const float* __restrict__ lng,  const float* __restrict__ lnb,
                          float* __restrict__ ws) {
    __shared__ float e[64];
    __shared__ float a1[128];
    int w = blockIdx.x;
    int tid = threadIdx.x;
    if (tid < 64) e[tid] = embed[w * 64 + tid];
    __syncthreads();
    float z1 = ffb1[tid];
    for (int x = 0; x < 64; ++x) z1 += e[x] * ffw1[x * 128 + tid];
    a1[tid] = fmaxf(z1, 0.0f);
    __syncthreads();
    if (tid < 64) {
        float f = ffb2[tid];
        for (int i = 0; i < 128; ++i) f += a1[i] * ffw2[i * 64 + tid];
        float hv = e[tid] + f;
        float s = hv;
#pragma unroll
        for (int m = 32; m >= 1; m >>= 1) s += __shfl_xor(s, m);
        float mu = s * (1.0f / 64.0f);
        float dv = hv - mu;
        float vs = dv * dv;
#pragma unroll
        for (int m = 32; m >= 1; m >>= 1) vs += __shfl_xor(vs, m);
        float rstd = 1.0f / sqrtf(vs * (1.0f / 64.0f) + EPSV);
        ws[WS_HS + w * 64 + tid] = dv * rstd * lng[tid] + lnb[tid];
    }
}

// ---------------- kernel B: pre-scaled Gram + Ztilde0, 64 blocks ----------------
__global__ void gz_kernel(const float* __restrict__ w1, const float* __restrict__ b1,
                          float* __restrict__ ws) {
    __shared__ float row[64];
    int w = blockIdx.x, tid = threadIdx.x;
    row[tid] = ws[WS_HS + w * 64 + tid];
    __syncthreads();
    float g = 0.0f;
    for (int x = 0; x < 64; ++x) g += row[x] * ws[WS_HS + tid * 64 + x];
    ws[WS_G + w * 64 + tid] = GAMMA * g + GAMMA;      // pre-scaled
    if (tid < 16) {
        float z = b1[tid];
        for (int x = 0; x < 64; ++x) z += row[x] * w1[x * 16 + tid];
        ws[WS_Z0 + w * 16 + tid] = z;
    }
}

// ---------------- main kernel: 4-wave j-split, register Z (R3 verified) + raw barrier ----------------
// R12 = exact revert to R10 (best verified: 258us kernel / 327us total).
// R11's trims (symmetric vv-fold, cr carry) were neutral-to-negative: both
// removed ops that were already hidden in the post-barrier shadow while adding
// pre-barrier issue + register pressure. Step floor: max(~300cy per-wave
// in-order issue, ~240cy LDS y round-trip + ~90cy serial DPP reduce) + barrier
// ~= 605cy x 1023 steps. All structural alternatives counter-tested and
// rejected: 1/2/8-wave splits, LDS-Z, factored/Gram/h-split reforms, fusion,
// wide-read exchange, asymmetric folds.
struct TTT4Smem {
    float hs[4096];
    float Gs[4096];
    int   sq[2048];                 // unguarded prefetch reads sq[2048..2049] -> land in ybuf (harmless)
    float ybuf[2][4][64];           // [parity][wave][lane] y-partial exchange
    float ctxp[4][64];              // final ctx partials
};

__device__ __forceinline__ void reduce4(const v2f* a2, const v2f* p2, v2f* dz2) {
    // fold lane bit0: partner lane's slot m^2 is the same logical j
    float q0 = p2[0].x + dppmov<0xB1>(p2[1].x);
    float q1 = p2[0].y + dppmov<0xB1>(p2[1].y);
    // relu mask (slot-aligned)
    float rm0 = (a2[0].x > 0.0f) ? q0 : 0.0f;
    float rm1 = (a2[0].y > 0.0f) ? q1 : 0.0f;
    // fold b4 (encodes q-index into b4) then sum over b5
    v2u f01 = swap16(rm0, rm1);
    float T = U2F(f01[0]) + U2F(f01[1]);        // j = b4 + 2*b0, summed over b4-pair
    v2u g01 = swap32(T, T);
    T = U2F(g01[0]) + U2F(g01[1]);              // summed over b5
    // orbit sums over lane bits 1,2,3
    T = T + dppmov<0x122>(T);   // row_ror:2
    T = T + dppmov<0x124>(T);   // row_ror:4
    T = T + dppmov<0x128>(T);   // row_ror:8
    // broadcast: T = dz[b4 + 2*b0] -> all 4 slots (slot m <-> j = m ^ 2*b0)
    v2u u01 = swap16(T, T);
    const float A0 = U2F(u01[0]);               // dz[0 ^ 2b0] -> slot 0
    const float A1 = U2F(u01[1]);               // dz[1 ^ 2b0] -> slot 1
    dz2[0] = {A0, A1};
    dz2[1] = {dppmov<0xB1>(A0), dppmov<0xB1>(A1)};   // slots 2,3 (other b0)
}

__launch_bounds__(256, 1)
__global__ void ttt_kernel(const int* __restrict__ seq,
                           const float* __restrict__ w2, const float* __restrict__ b2i,
                           const float* __restrict__ outw, const float* __restrict__ outb,
                           const float* __restrict__ ws, float* __restrict__ out) {
    __shared__ TTT4Smem sm;

    const int b    = blockIdx.x;
    const int tid  = threadIdx.x;
    const int wv   = tid >> 6;
    const int lane = tid & 63;
    const int b0   = lane & 1;
    const int X    = b0 << 1;              // slot xor: logical j = 4*wv + (slot ^ X)
    const bool pb  = (b0 != 0);
    const bool wv0 = (wv == 0);

    {   // vectorized staging (256 threads)
        float4*       hv = (float4*)sm.hs;
        const float4* sv = (const float4*)(ws + WS_HS);
#pragma unroll
        for (int m = 0; m < 4; ++m) hv[m * 256 + tid] = sv[m * 256 + tid];
        float4*       gv = (float4*)sm.Gs;
        const float4* gs = (const float4*)(ws + WS_G);
#pragma unroll
        for (int m = 0; m < 4; ++m) gv[m * 256 + tid] = gs[m * 256 + tid];
        int4*       qv = (int4*)sm.sq;
        const int4* qs = (const int4*)(seq + b * 2048);
#pragma unroll
        for (int m = 0; m < 2; ++m) qv[m * 256 + tid] = qs[m * 256 + tid];
    }

    // Z state: row = lane, this wave's 4 j-columns, LOGICAL order, registers only
    v2f Zv[2];
    {
        const float4 z0 = *(const float4*)(ws + WS_Z0 + lane * 16 + 4 * wv);
        Zv[0] = {z0.x, z0.y};
        Zv[1] = {z0.z, z0.w};
    }

    // W2 in permuted slot order for this wave's j-slice
    v2f W2p[2];
#pragma unroll
    for (int i = 0; i < 2; ++i) {
        v2f w;
        w.x = w2[(4 * wv + ((2 * i) ^ X)) * 64 + lane];
        w.y = w2[(4 * wv + ((2 * i + 1) ^ X)) * 64 + lane];
        W2p[i] = w;
    }
    float ybias = wv0 ? b2i[lane] : 0.0f;     // b2 lives in wave0's y-partial only
    const float gma = wv0 ? GAMMA : 0.0f;
    __syncthreads();                          // staging barrier: full drain (kept)

    // z2 init: row sq[0] broadcast from registers via readlane, permuted slots
    int tk = sm.sq[0];
    v2f z2[2];
    {
        const int stk = __builtin_amdgcn_readfirstlane(tk);
        const float e0 = rlane(Zv[0].x, stk);
        const float e1 = rlane(Zv[0].y, stk);
        const float e2 = rlane(Zv[1].x, stk);
        const float e3 = rlane(Zv[1].y, stk);
        z2[0] = { pb ? e2 : e0, pb ? e3 : e1 };
        z2[1] = { pb ? e0 : e2, pb ? e1 : e3 };
    }
    float vv = sm.hs[sm.sq[1] * 64 + lane];

    int2 pairT  = *(const int2*)(sm.sq + 2);
    int2 pairT1 = *(const int2*)(sm.sq + 4);

    // main loop: steps 0..1021 (last step peeled)
#pragma unroll 2
    for (int t = 0; t < TSTEPS - 1; ++t) {
        const int tkn = pairT.x;
        const int tvn = pairT.y;
        const int par = t & 1;

        // ---- forward on own j-slice ----
        const v2f zero2 = {0.0f, 0.0f};
        v2f a2[2];
        a2[0] = __builtin_elementwise_max(z2[0], zero2);
        a2[1] = __builtin_elementwise_max(z2[1], zero2);
        v2f accv = a2[0] * W2p[0] + a2[1] * W2p[1];
        const float ypart = ybias + accv.x + accv.y;

        // ---- y exchange (parity ping-pong, RAW barrier: no pre-drain) ----
        sm.ybuf[par][wv][lane] = ypart;
        xbar();
        const float y0 = sm.ybuf[par][0][lane];
        const float y1 = sm.ybuf[par][1][lane];
        const float y2 = sm.ybuf[par][2][lane];
        const float y3 = sm.ybuf[par][3][lane];

        // ---- off-chain: prefetch reads + register-Z row broadcast ----
        const float vnext = sm.hs[tvn * 64 + lane];
        const float cr = sm.Gs[tk * 64 + lane];     // pre-scaled gamma*(G+1), row tk
        const int2 pairT2 = *(const int2*)(sm.sq + 2 * t + 6);  // t=1021 reads ybuf: unused
        const int stkn = __builtin_amdgcn_readfirstlane(tkn);
        const float e0 = rlane(Zv[0].x, stkn);      // Zv current through t-1
        const float e1 = rlane(Zv[0].y, stkn);
        const float e2 = rlane(Zv[1].x, stkn);
        const float e3 = rlane(Zv[1].y, stkn);
        const v2f E0 = { pb ? e2 : e0, pb ? e3 : e1 };   // permuted slot order
        const v2f E1 = { pb ? e0 : e2, pb ? e1 : e3 };
        const float cz = rlane(cr, stkn);           // Gs[tk*64 + tkn]

        // ---- d (fixed tree -> bitwise identical in all 4 waves) ----
        const float d = ((y0 + y1) + (y2 + y3)) - vv;

        // ---- p (pre-update W2) + local W2/b2 update ----
        const v2f d2 = {d, d};
        v2f p2[2];
        p2[0] = W2p[0] * d2;
        p2[1] = W2p[1] * d2;
        const float sd = GAMMA * d;
        ybias -= gma * d;
        const v2f sd2 = {sd, sd};
        W2p[0] = W2p[0] - sd2 * a2[0];
        W2p[1] = W2p[1] - sd2 * a2[1];

        // ---- cross-lane reduction + broadcast ----
        v2f dz2[2];
        reduce4(a2, p2, dz2);

        // ---- next-token state (table lag covered by cz term) ----
        const v2f cz2 = {cz, cz};
        z2[0] = E0 - cz2 * dz2[0];
        z2[1] = E1 - cz2 * dz2[1];

        // ---- prompt register-Z update (logical order) ----
        const v2f dzl0 = pb ? dz2[1] : dz2[0];
        const v2f dzl1 = pb ? dz2[0] : dz2[1];
        const v2f cr2 = {cr, cr};
        Zv[0] = Zv[0] - cr2 * dzl0;
        Zv[1] = Zv[1] - cr2 * dzl1;

        vv = vnext;
        tk = tkn;
        pairT = pairT1;
        pairT1 = pairT2;
    }

    // ---- peeled final step (t = 1022): tkn = query token sq[2047] ----
    {
        const int tkn = pairT.y;                  // pairT = {sq[2046], sq[2047]}
        const v2f zero2 = {0.0f, 0.0f};
        v2f a2[2];
        a2[0] = __builtin_elementwise_max(z2[0], zero2);
        a2[1] = __builtin_elementwise_max(z2[1], zero2);
        v2f accv = a2[0] * W2p[0] + a2[1] * W2p[1];
        const float ypart = ybias + accv.x + accv.y;

        sm.ybuf[0][wv][lane] = ypart;             // 1022 even -> parity 0
        xbar();
        const float y0 = sm.ybuf[0][0][lane];
        const float y1 = sm.ybuf[0][1][lane];
        const float y2 = sm.ybuf[0][2][lane];
        const float y3 = sm.ybuf[0][3][lane];

        const float cr = sm.Gs[tk * 64 + lane];
        const int stkn = __builtin_amdgcn_readfirstlane(tkn);
        const float e0 = rlane(Zv[0].x, stkn);    // Zv current through step 1021
        const float e1 = rlane(Zv[0].y, stkn);
        const float e2 = rlane(Zv[1].x, stkn);
        const float e3 = rlane(Zv[1].y, stkn);
        const v2f E0 = { pb ? e2 : e0, pb ? e3 : e1 };
        const v2f E1 = { pb ? e0 : e2, pb ? e1 : e3 };
        const float cz = rlane(cr, stkn);

        const float d = ((y0 + y1) + (y2 + y3)) - vv;

        const v2f d2 = {d, d};
        v2f p2[2];
        p2[0] = W2p[0] * d2;
        p2[1] = W2p[1] * d2;
        const float sd = GAMMA * d;
        ybias -= gma * d;
        const v2f sd2 = {sd, sd};
        W2p[0] = W2p[0] - sd2 * a2[0];
        W2p[1] = W2p[1] - sd2 * a2[1];

        v2f dz2[2];
        reduce4(a2, p2, dz2);

        const v2f cz2 = {cz, cz};
        z2[0] = E0 - cz2 * dz2[0];
        z2[1] = E1 - cz2 * dz2[1];
    }

    // ---- final eval: ctx partial per wave, combine, then out matvec ----
    {
        const v2f zero2 = {0.0f, 0.0f};
        v2f acc = __builtin_elementwise_max(z2[0], zero2) * W2p[0]
                + __builtin_elementwise_max(z2[1], zero2) * W2p[1];
        sm.ctxp[wv][lane] = ybias + acc.x + acc.y;
    }
    __syncthreads();                              // epilogue barrier: full drain (kept)
    if (wv0) {
        float o = outb[lane];
        for (int hh = 0; hh < 64; ++hh)
            o += (sm.ctxp[0][hh] + sm.ctxp[1][hh] + sm.ctxp[2][hh] + sm.ctxp[3][hh])
                 * outw[hh * 64 + lane];
        out[b * 64 + lane] = o;
    }
}

// ---------------- launcher ----------------
extern "C" void kernel_launch(void* const* d_in, const int* in_sizes, int n_in,
                              void* d_out, int out_size, void* d_ws, size_t ws_size,
                              hipStream_t stream) {
    const int*   seq   = (const int*)d_in[0];
    const float* embed = (const float*)d_in[1];
    const float* ffw1  = (const float*)d_in[2];
    const float* ffb1  = (const float*)d_in[3];
    const float* ffw2  = (const float*)d_in[4];
    const float* ffb2  = (const float*)d_in[5];
    const float* lng   = (const float*)d_in[6];
    const float* lnb   = (const float*)d_in[7];
    const float* w1    = (const float*)d_in[8];
    const float* b1    = (const float*)d_in[9];
    const float* w2    = (const float*)d_in[10];
    const float* b2    = (const float*)d_in[11];
    const float* outw  = (const float*)d_in[12];
    const float* outb  = (const float*)d_in[13];
    float* ws  = (float*)d_ws;
    float* out = (float*)d_out;

    hipLaunchKernelGGL(hs_kernel, dim3(64), dim3(128), 0, stream,
                       embed, ffw1, ffb1, ffw2, ffb2, lng, lnb, ws);
    hipLaunchKernelGGL(gz_kernel, dim3(64), dim3(64), 0, stream, w1, b1, ws);
    hipLaunchKernelGGL(ttt_kernel, dim3(256), dim3(256), 0, stream,
                       seq, w2, b2, outw, outb, ws, out);
}